// Round 8
// baseline (236.018 us; speedup 1.0000x reference)
//
#include <hip/hip_runtime.h>
#include <math.h>

#define B_   2
#define L_   2048
#define EMB_ 1024
#define H_   16
#define HD_  64
#define M_   (B_ * L_)   // 4096 tokens
#define KSPLIT 4
#define LOG2E 1.44269504088896f

typedef __bf16 bf16x8 __attribute__((ext_vector_type(8)));
typedef __bf16 bf16x4 __attribute__((ext_vector_type(4)));
typedef __bf16 bf16x2 __attribute__((ext_vector_type(2)));
typedef float floatx16 __attribute__((ext_vector_type(16)));

typedef __attribute__((address_space(1))) const void GV;
typedef __attribute__((address_space(3))) void LV;

#define MFMA32(a, b, c) __builtin_amdgcn_mfma_f32_32x32x16_bf16((a), (b), (c), 0, 0, 0)

#if __has_builtin(__builtin_amdgcn_exp2f)
#define EXP2(x) __builtin_amdgcn_exp2f(x)
#else
#define EXP2(x) exp2f(x)
#endif

// LDS chunk swizzle: lanes lq, lq+8, lq+16, lq+24 (same (row&7)) get distinct
// chunk slots via the (row>>3)&3 term.
#define SWZ(row) ((((row) & 7) ^ (((row) >> 3) & 3)))

// pack two floats into a bf16 pair (b32)
__device__ __forceinline__ int pkbf(float a, float b) {
#if __has_builtin(__builtin_amdgcn_cvt_pk_bf16_f32)
    union { bf16x2 v; int i; } u;
    u.v = __builtin_amdgcn_cvt_pk_bf16_f32(a, b);
    return u.i;
#else
    union { __bf16 h[2]; int i; } u;
    u.h[0] = (__bf16)a; u.h[1] = (__bf16)b;
    return u.i;
#endif
}

// ---------------------------------------------------------------------------
// Weight fp32 -> bf16 conversion (4 targets, grid.y selects).
// d0..d2 are the fused QKV weight slabs, d3 = Wo.
// ---------------------------------------------------------------------------
__global__ __launch_bounds__(256) void cvt_w_kernel(
        const float* __restrict__ s0, const float* __restrict__ s1,
        const float* __restrict__ s2, const float* __restrict__ s3,
        __bf16* __restrict__ d0, __bf16* __restrict__ d1,
        __bf16* __restrict__ d2, __bf16* __restrict__ d3) {
    int z = blockIdx.y;
    const float* s = (z == 0) ? s0 : (z == 1) ? s1 : (z == 2) ? s2 : s3;
    __bf16* d = (z == 0) ? d0 : (z == 1) ? d1 : (z == 2) ? d2 : d3;
    size_t base = (size_t)(blockIdx.x * 256 + threadIdx.x) * 16;
#pragma unroll
    for (int j = 0; j < 4; ++j) {
        float4 f = *(const float4*)(s + base + j * 4);
        bf16x4 t;
        t[0] = (__bf16)f.x; t[1] = (__bf16)f.y; t[2] = (__bf16)f.z; t[3] = (__bf16)f.w;
        *(bf16x4*)(d + base + j * 4) = t;
    }
}

// ---------------------------------------------------------------------------
// LayerNorm -> bf16. One 256-thread block per token row
// ---------------------------------------------------------------------------
__global__ __launch_bounds__(256) void ln_kernel(
        const float* __restrict__ x, const float* __restrict__ gamma,
        const float* __restrict__ beta, __bf16* __restrict__ h) {
    int row = blockIdx.x;
    int tid = threadIdx.x;
    const float* xr = x + (size_t)row * EMB_;
    float4 v = *(const float4*)(xr + tid * 4);
    float s  = v.x + v.y + v.z + v.w;
    float ss = v.x * v.x + v.y * v.y + v.z * v.z + v.w * v.w;
    for (int off = 32; off; off >>= 1) {
        s  += __shfl_down(s, off, 64);
        ss += __shfl_down(ss, off, 64);
    }
    __shared__ float s1[4], s2[4];
    int wid = tid >> 6;
    if ((tid & 63) == 0) { s1[wid] = s; s2[wid] = ss; }
    __syncthreads();
    if (tid == 0) {
        float a = s1[0] + s1[1] + s1[2] + s1[3];
        float b = s2[0] + s2[1] + s2[2] + s2[3];
        float mu = a / EMB_;
        float var = b / EMB_ - mu * mu;
        s1[0] = mu;
        s2[0] = rsqrtf(var + 1e-5f);
    }
    __syncthreads();
    float mu = s1[0], rstd = s2[0];
    float4 g4 = *(const float4*)(gamma + tid * 4);
    float4 b4 = *(const float4*)(beta + tid * 4);
    bf16x4 o;
    o[0] = (__bf16)((v.x - mu) * rstd * g4.x + b4.x);
    o[1] = (__bf16)((v.y - mu) * rstd * g4.y + b4.y);
    o[2] = (__bf16)((v.z - mu) * rstd * g4.z + b4.z);
    o[3] = (__bf16)((v.w - mu) * rstd * g4.w + b4.w);
    *(bf16x4*)(h + (size_t)row * EMB_ + tid * 4) = o;
}

// ---------------------------------------------------------------------------
// GEMM staging: 128 rows x 64 cols bf16 tile, SWZ-swizzled 16B chunks.
// ---------------------------------------------------------------------------
__device__ __forceinline__ void stage_tile128(const __bf16* gbase, __bf16* lds,
                                              int wave, int lane) {
    int srow = lane >> 3;
    int gch0 = lane & 7;
#pragma unroll
    for (int s = 0; s < 4; ++s) {
        int seg = wave * 4 + s;
        int row = seg * 8 + srow;
        int g = gch0 ^ SWZ(row);
        __builtin_amdgcn_global_load_lds(
            (GV*)(gbase + (size_t)row * EMB_ + g * 8),
            (LV*)(lds + seg * 512 + lane * 8), 16, 0, 0);
    }
}

// ---------------------------------------------------------------------------
// Fused QKV projection GEMM: C = h @ Wqkv^T + bias, 128x128 tile, BK=64.
// Wqkv = [3072][1024] (Wq; Wk; Wv). Column block z = col>>10 selects output:
// z=0 -> Q (scaled by 0.125*log2e), z=1 -> K, z=2 -> V^T ([b][h][d][l]).
// ---------------------------------------------------------------------------
__global__ __launch_bounds__(256) void gemm_qkv_mfma(
        const __bf16* __restrict__ A, const __bf16* __restrict__ W,
        const float* __restrict__ bq, const float* __restrict__ bk,
        const float* __restrict__ bv,
        __bf16* __restrict__ Qo, __bf16* __restrict__ Ko,
        __bf16* __restrict__ Vto) {
    __shared__ __bf16 As[128 * 64];
    __shared__ __bf16 Bs[128 * 64];
    int tid = threadIdx.x, wave = tid >> 6, lane = tid & 63;
    int wm = wave >> 1, wn = wave & 1;
    int quad = lane >> 5, lq = lane & 31;
    int bm = blockIdx.y * 128, bn = blockIdx.x * 128;

    floatx16 acc[2][2];
#pragma unroll
    for (int i = 0; i < 2; ++i)
#pragma unroll
        for (int j = 0; j < 2; ++j)
#pragma unroll
            for (int r = 0; r < 16; ++r) acc[i][j][r] = 0.f;

    for (int k0 = 0; k0 < EMB_; k0 += 64) {
        __syncthreads();
        stage_tile128(A + (size_t)bm * EMB_ + k0, As, wave, lane);
        stage_tile128(W + (size_t)bn * EMB_ + k0, Bs, wave, lane);
        __syncthreads();
#pragma unroll
        for (int s = 0; s < 4; ++s) {
            int g = 2 * s + quad;
            int r0 = wm * 64 + lq, r1 = r0 + 32;
            int c0 = wn * 64 + lq, c1 = c0 + 32;
            bf16x8 a0 = *(const bf16x8*)&As[r0 * 64 + ((g ^ SWZ(r0)) * 8)];
            bf16x8 a1 = *(const bf16x8*)&As[r1 * 64 + ((g ^ SWZ(r1)) * 8)];
            bf16x8 b0 = *(const bf16x8*)&Bs[c0 * 64 + ((g ^ SWZ(c0)) * 8)];
            bf16x8 b1 = *(const bf16x8*)&Bs[c1 * 64 + ((g ^ SWZ(c1)) * 8)];
            acc[0][0] = MFMA32(a0, b0, acc[0][0]);
            acc[0][1] = MFMA32(a0, b1, acc[0][1]);
            acc[1][0] = MFMA32(a1, b0, acc[1][0]);
            acc[1][1] = MFMA32(a1, b1, acc[1][1]);
        }
    }

#pragma unroll
    for (int mb = 0; mb < 2; ++mb) {
#pragma unroll
        for (int nb = 0; nb < 2; ++nb) {
            int col = bn + wn * 64 + nb * 32 + lq;
            int z = col >> 10;
            int cc = col & 1023;
            float bv_ = (z == 0) ? bq[cc] : (z == 1) ? bk[cc] : bv[cc];
            if (z < 2) {
                __bf16* dst = (z == 0) ? Qo : Ko;
                float qs = (z == 0) ? 0.125f * LOG2E : 1.0f;
#pragma unroll
                for (int r = 0; r < 16; ++r) {
                    int row = bm + wm * 64 + mb * 32 + (r & 3) + 8 * (r >> 2) + 4 * quad;
                    dst[(size_t)row * EMB_ + cc] = (__bf16)((acc[mb][nb][r] + bv_) * qs);
                }
            } else {
                int hh = cc >> 6, d = cc & 63;
#pragma unroll
                for (int rb = 0; rb < 4; ++rb) {
                    int row = bm + wm * 64 + mb * 32 + 8 * rb + 4 * quad;
                    int b = row >> 11, l = row & (L_ - 1);
                    bf16x4 t;
#pragma unroll
                    for (int a = 0; a < 4; ++a) t[a] = (__bf16)(acc[mb][nb][4 * rb + a] + bv_);
                    *(bf16x4*)(Vto + ((size_t)(b * H_ + hh) * HD_ + d) * L_ + l) = t;
                }
            }
        }
    }
}

// ---------------------------------------------------------------------------
// Output projection GEMM: out = O @ Wo^T + bo + x (fp32 out). 64x128 tile.
// ---------------------------------------------------------------------------
template <int SEGS>
__device__ __forceinline__ void stage_tile(const __bf16* gbase, __bf16* lds,
                                           int wave, int lane) {
    int srow = lane >> 3;
    int gch0 = lane & 7;
#pragma unroll
    for (int s = 0; s < SEGS; ++s) {
        int seg = wave * SEGS + s;
        int row = seg * 8 + srow;
        int g = gch0 ^ SWZ(row);
        __builtin_amdgcn_global_load_lds(
            (GV*)(gbase + (size_t)row * EMB_ + g * 8),
            (LV*)(lds + seg * 512 + lane * 8), 16, 0, 0);
    }
}

__global__ __launch_bounds__(256) void gemm_out_mfma(
        const __bf16* __restrict__ A, const __bf16* __restrict__ W,
        const float* __restrict__ bias, const float* __restrict__ x,
        float* __restrict__ out) {
    __shared__ __bf16 As[64 * 64];
    __shared__ __bf16 Bs[128 * 64];
    int tid = threadIdx.x, wave = tid >> 6, lane = tid & 63;
    int quad = lane >> 5, lq = lane & 31;
    int bm = blockIdx.y * 64, bn = blockIdx.x * 128;

    floatx16 acc[2];
#pragma unroll
    for (int i = 0; i < 2; ++i)
#pragma unroll
        for (int r = 0; r < 16; ++r) acc[i][r] = 0.f;

    for (int k0 = 0; k0 < EMB_; k0 += 64) {
        __syncthreads();
        stage_tile<2>(A + (size_t)bm * EMB_ + k0, As, wave, lane);
        stage_tile<4>(W + (size_t)bn * EMB_ + k0, Bs, wave, lane);
        __syncthreads();
#pragma unroll
        for (int s = 0; s < 4; ++s) {
            int g = 2 * s + quad;
            int r0 = lq, r1 = lq + 32;
            int c = wave * 32 + lq;
            bf16x8 a0 = *(const bf16x8*)&As[r0 * 64 + ((g ^ SWZ(r0)) * 8)];
            bf16x8 a1 = *(const bf16x8*)&As[r1 * 64 + ((g ^ SWZ(r1)) * 8)];
            bf16x8 b  = *(const bf16x8*)&Bs[c * 64 + ((g ^ SWZ(c)) * 8)];
            acc[0] = MFMA32(a0, b, acc[0]);
            acc[1] = MFMA32(a1, b, acc[1]);
        }
    }

    int col = bn + wave * 32 + lq;
    float bv_ = bias[col];
#pragma unroll
    for (int mb = 0; mb < 2; ++mb) {
#pragma unroll
        for (int r = 0; r < 16; ++r) {
            size_t row = bm + mb * 32 + (r & 3) + 8 * (r >> 2) + 4 * quad;
            out[row * EMB_ + col] = acc[mb][r] + bv_ + x[row * EMB_ + col];
        }
    }
}

// ---------------------------------------------------------------------------
// LDS-staged, double-buffered MFMA flash attention.
// Block = 256 thr (4 waves), each wave owns 64 queries (block: 256 q).
// Per 64-key tile: K [64 keys][64 d] and V^T [64 d][64 keys] staged via
// global_load_lds (coalesced), fragments read b128 with SWZ swizzle.
// S^T = MFMA(K-frag, Q-frag): per-lane l; P fix-up via quad-half shuffle;
// O^T accumulated; partials in C-layout [d][q] + combine kernel.
// blockIdx.x = bh -> per-head K/V stays XCD-local.
// ---------------------------------------------------------------------------
__global__ __launch_bounds__(256) void attn_mfma(
        const __bf16* __restrict__ Q,   // [4096][1024], pre-scaled
        const __bf16* __restrict__ K,   // [4096][1024]
        const __bf16* __restrict__ Vt,  // [bh][64][2048]
        __bf16* __restrict__ Op,        // [KSPLIT][bh][64][2048]
        float* __restrict__ Lp) {       // [KSPLIT][bh][2048]
    __shared__ __bf16 Ks[2][64 * 64];
    __shared__ __bf16 Vs[2][64 * 64];

    int tid = threadIdx.x, wave = tid >> 6, lane = tid & 63;
    int quad = lane >> 5, lq = lane & 31;
    int bh = blockIdx.x;
    int ks = blockIdx.z;
    int b = bh >> 4, h = bh & 15;
    int q0 = blockIdx.y * 256 + wave * 64;
    const size_t tok0 = (size_t)b * L_;

    const __bf16* Kb = K + tok0 * EMB_ + h * HD_;
    const __bf16* Vb = Vt + (size_t)bh * HD_ * L_;

    // Q fragments: B-operand, 2 query blocks x 4 k-steps
    bf16x8 qf[2][4];
#pragma unroll
    for (int qb = 0; qb < 2; ++qb) {
        const __bf16* qp = Q + (tok0 + q0 + qb * 32 + lq) * EMB_ + h * HD_ + quad * 8;
#pragma unroll
        for (int s = 0; s < 4; ++s) qf[qb][s] = *(const bf16x8*)(qp + s * 16);
    }

    floatx16 oacc[2][2];   // [qb][db]
#pragma unroll
    for (int i = 0; i < 2; ++i)
#pragma unroll
        for (int j = 0; j < 2; ++j)
#pragma unroll
            for (int r = 0; r < 16; ++r) oacc[i][j][r] = 0.f;
    float lacc[2] = {0.f, 0.f};

    int srow = lane >> 3, gch0 = lane & 7;

    auto stage = [&](int buf, int kt) {
#pragma unroll
        for (int s = 0; s < 2; ++s) {
            int seg = wave * 2 + s;
            int row = seg * 8 + srow;
            int g = gch0 ^ SWZ(row);
            __builtin_amdgcn_global_load_lds(
                (GV*)(Kb + (size_t)(kt + row) * EMB_ + g * 8),
                (LV*)(&Ks[buf][seg * 512 + lane * 8]), 16, 0, 0);
            __builtin_amdgcn_global_load_lds(
                (GV*)(Vb + (size_t)row * L_ + kt + g * 8),
                (LV*)(&Vs[buf][seg * 512 + lane * 8]), 16, 0, 0);
        }
    };

    auto compute = [&](int buf) {
#pragma unroll
        for (int nb = 0; nb < 2; ++nb) {
            // K fragments (A-operand) for this 32-key block
            int krow = nb * 32 + lq;
            bf16x8 kf[4];
#pragma unroll
            for (int s = 0; s < 4; ++s)
                kf[s] = *(const bf16x8*)&Ks[buf][krow * 64 + (((2 * s + quad) ^ SWZ(krow)) * 8)];
            // V^T fragments for the two 16-key PV steps of this block
            bf16x8 vf[2][2];
#pragma unroll
            for (int half = 0; half < 2; ++half) {
                int t = 2 * nb + half;
#pragma unroll
                for (int db = 0; db < 2; ++db) {
                    int drow = db * 32 + lq;
                    vf[half][db] = *(const bf16x8*)&Vs[buf][drow * 64 + (((2 * t + quad) ^ SWZ(drow)) * 8)];
                }
            }
#pragma unroll
            for (int qb = 0; qb < 2; ++qb) {
                floatx16 sacc;
#pragma unroll
                for (int r = 0; r < 16; ++r) sacc[r] = 0.f;
#pragma unroll
                for (int s = 0; s < 4; ++s) sacc = MFMA32(kf[s], qf[qb][s], sacc);

                int P[8];
                float lsum = 0.f;
#pragma unroll
                for (int t = 0; t < 8; ++t) {
                    float pa = EXP2(sacc[2 * t]);
                    float pb = EXP2(sacc[2 * t + 1]);
                    lsum += pa + pb;
                    P[t] = pkbf(pa, pb);
                }
                lacc[qb] += lsum;
                int X[8];
#pragma unroll
                for (int t = 0; t < 8; ++t) X[t] = __shfl_xor(P[t], 32, 64);
                union { int i[4]; bf16x8 v; } bf0, bf1;
                bf0.i[0] = quad ? X[2] : P[0];
                bf0.i[1] = quad ? X[3] : P[1];
                bf0.i[2] = quad ? P[2] : X[0];
                bf0.i[3] = quad ? P[3] : X[1];
                bf1.i[0] = quad ? X[6] : P[4];
                bf1.i[1] = quad ? X[7] : P[5];
                bf1.i[2] = quad ? P[6] : X[4];
                bf1.i[3] = quad ? P[7] : X[5];
#pragma unroll
                for (int db = 0; db < 2; ++db) {
                    oacc[qb][db] = MFMA32(vf[0][db], bf0.v, oacc[qb][db]);
                    oacc[qb][db] = MFMA32(vf[1][db], bf1.v, oacc[qb][db]);
                }
            }
        }
    };

    const int kt0 = ks * (L_ / KSPLIT);
    const int NT = (L_ / KSPLIT) / 64;   // 8 tiles of 64 keys

    stage(0, kt0);
    for (int t = 0; t < NT; ++t) {
        __syncthreads();                  // buf[t&1] staged (vmcnt drained)
        if (t + 1 < NT) stage((t + 1) & 1, kt0 + (t + 1) * 64);
        compute(t & 1);
    }

    // denominators: combine quad halves; lane<32 stores both query blocks
#pragma unroll
    for (int qb = 0; qb < 2; ++qb) {
        float l = lacc[qb] + __shfl_xor(lacc[qb], 32, 64);
        if (lane < 32)
            Lp[((size_t)ks * 32 + bh) * L_ + q0 + qb * 32 + lane] = l;
    }
    // store O^T partials in C-layout [d][q] (col q contiguous across lanes)
#pragma unroll
    for (int qb = 0; qb < 2; ++qb)
#pragma unroll
        for (int db = 0; db < 2; ++db)
#pragma unroll
            for (int r = 0; r < 16; ++r) {
                int dp = db * 32 + (r & 3) + 8 * (r >> 2) + 4 * quad;
                Op[((size_t)(ks * 32 + bh) * HD_ + dp) * L_ + q0 + qb * 32 + lq] =
                    (__bf16)oacc[qb][db][r];
            }
}

// ---------------------------------------------------------------------------
// Combine split-K partials + transpose to token-major.
// ---------------------------------------------------------------------------
__global__ __launch_bounds__(256) void combine_kernel(
        const __bf16* __restrict__ Op, const float* __restrict__ Lp,
        __bf16* __restrict__ Ob) {
    __shared__ float lrl[64];
    __shared__ __bf16 T[64][72];   // [q][d]
    int t = threadIdx.x;
    int qt = blockIdx.x * 64;
    int bh = blockIdx.y;
    int b = bh >> 4, h = bh & 15;

    if (t < 64) {
        float l = 0.f;
#pragma unroll
        for (int ks = 0; ks < KSPLIT; ++ks)
            l += Lp[((size_t)ks * 32 + bh) * L_ + qt + t];
        lrl[t] = 1.0f / l;
    }
    __syncthreads();

#pragma unroll
    for (int cc = 0; cc < 2; ++cc) {
        int id = t + cc * 256;          // 0..511
        int d = id >> 3, q8 = (id & 7) * 8;
        float acc[8];
#pragma unroll
        for (int j = 0; j < 8; ++j) acc[j] = 0.f;
#pragma unroll
        for (int ks = 0; ks < KSPLIT; ++ks) {
            bf16x8 v = *(const bf16x8*)(Op + ((size_t)(ks * 32 + bh) * HD_ + d) * L_ + qt + q8);
#pragma unroll
            for (int j = 0; j < 8; ++j) acc[j] += (float)v[j];
        }
#pragma unroll
        for (int j = 0; j < 8; ++j)
            T[q8 + j][d] = (__bf16)(acc[j] * lrl[q8 + j]);
    }
    __syncthreads();

#pragma unroll
    for (int cc = 0; cc < 2; ++cc) {
        int id = t + cc * 256;
        int tl = id >> 3, dc = (id & 7) * 8;
        bf16x8 v = *(const bf16x8*)&T[tl][dc];
        *(bf16x8*)(Ob + ((size_t)b * L_ + qt + tl) * EMB_ + h * HD_ + dc) = v;
    }
}

// ---------------------------------------------------------------------------
extern "C" void kernel_launch(void* const* d_in, const int* in_sizes, int n_in,
                              void* d_out, int out_size, void* d_ws, size_t ws_size,
                              hipStream_t stream) {
    const float* x     = (const float*)d_in[0];
    const float* gamma = (const float*)d_in[1];
    const float* beta  = (const float*)d_in[2];
    const float* Wq    = (const float*)d_in[3];
    const float* bq    = (const float*)d_in[4];
    const float* Wk    = (const float*)d_in[5];
    const float* bk    = (const float*)d_in[6];
    const float* Wv    = (const float*)d_in[7];
    const float* bv    = (const float*)d_in[8];
    const float* Wo    = (const float*)d_in[9];
    const float* bo    = (const float*)d_in[10];
    float* out = (float*)d_out;

    const size_t SLAB = (size_t)M_ * EMB_;        // activation elements
    const size_t WSLAB = (size_t)EMB_ * EMB_;     // weight elements
    char* ws = (char*)d_ws;
    __bf16* hb    = (__bf16*)ws;                      ws += SLAB * 2;
    __bf16* Qb    = (__bf16*)ws;                      ws += SLAB * 2;
    __bf16* Kb    = (__bf16*)ws;                      ws += SLAB * 2;
    __bf16* Vtb   = (__bf16*)ws;                      ws += SLAB * 2;
    __bf16* Wqkvb = (__bf16*)ws;                      ws += 3 * WSLAB * 2;
    __bf16* Wob   = (__bf16*)ws;                      ws += WSLAB * 2;
    __bf16* Op    = (__bf16*)ws;                      ws += (size_t)KSPLIT * SLAB * 2;
    float*  Lp    = (float*)ws;                       ws += (size_t)KSPLIT * 32 * L_ * 4;
    __bf16* Ob    = hb;   // hb dead after gemm_qkv; reuse for attention output

    cvt_w_kernel<<<dim3(256, 4), 256, 0, stream>>>(
        Wq, Wk, Wv, Wo, Wqkvb, Wqkvb + WSLAB, Wqkvb + 2 * WSLAB, Wob);
    ln_kernel<<<M_, 256, 0, stream>>>(x, gamma, beta, hb);
    gemm_qkv_mfma<<<dim3(3 * EMB_ / 128, M_ / 128), 256, 0, stream>>>(
        hb, Wqkvb, bq, bk, bv, Qb, Kb, Vtb);
    attn_mfma<<<dim3(B_ * H_, L_ / 256, KSPLIT), 256, 0, stream>>>(Qb, Kb, Vtb, Op, Lp);
    combine_kernel<<<dim3(L_ / 64, B_ * H_), 256, 0, stream>>>(Op, Lp, Ob);
    gemm_out_mfma<<<dim3(EMB_ / 128, M_ / 64), 256, 0, stream>>>(Ob, Wob, bo, x, out);
}

// Round 11
// 207.125 us; speedup vs baseline: 1.1395x; 1.1395x over previous
//
#include <hip/hip_runtime.h>
#include <math.h>

#define B_   2
#define L_   2048
#define EMB_ 1024
#define H_   16
#define HD_  64
#define M_   (B_ * L_)   // 4096 tokens
#define KSPLIT 4
#define LOG2E 1.44269504088896f

typedef __bf16 bf16x8 __attribute__((ext_vector_type(8)));
typedef __bf16 bf16x4 __attribute__((ext_vector_type(4)));
typedef __bf16 bf16x2 __attribute__((ext_vector_type(2)));
typedef float floatx16 __attribute__((ext_vector_type(16)));

typedef __attribute__((address_space(1))) const void GV;
typedef __attribute__((address_space(3))) void LV;

#define MFMA32(a, b, c) __builtin_amdgcn_mfma_f32_32x32x16_bf16((a), (b), (c), 0, 0, 0)

#if __has_builtin(__builtin_amdgcn_exp2f)
#define EXP2(x) __builtin_amdgcn_exp2f(x)
#else
#define EXP2(x) exp2f(x)
#endif

// LDS chunk swizzle: lanes lq, lq+8, lq+16, lq+24 (same (row&7)) get distinct
// chunk slots via the (row>>3)&3 term.
#define SWZ(row) ((((row) & 7) ^ (((row) >> 3) & 3)))

// pack two floats into a bf16 pair (b32)
__device__ __forceinline__ int pkbf(float a, float b) {
#if __has_builtin(__builtin_amdgcn_cvt_pk_bf16_f32)
    union { bf16x2 v; int i; } u;
    u.v = __builtin_amdgcn_cvt_pk_bf16_f32(a, b);
    return u.i;
#else
    union { __bf16 h[2]; int i; } u;
    u.h[0] = (__bf16)a; u.h[1] = (__bf16)b;
    return u.i;
#endif
}

// ---------------------------------------------------------------------------
// Weight fp32 -> bf16 conversion (4 targets, grid.y selects).
// d0..d2 are the fused QKV weight slabs, d3 = Wo.
// ---------------------------------------------------------------------------
__global__ __launch_bounds__(256) void cvt_w_kernel(
        const float* __restrict__ s0, const float* __restrict__ s1,
        const float* __restrict__ s2, const float* __restrict__ s3,
        __bf16* __restrict__ d0, __bf16* __restrict__ d1,
        __bf16* __restrict__ d2, __bf16* __restrict__ d3) {
    int z = blockIdx.y;
    const float* s = (z == 0) ? s0 : (z == 1) ? s1 : (z == 2) ? s2 : s3;
    __bf16* d = (z == 0) ? d0 : (z == 1) ? d1 : (z == 2) ? d2 : d3;
    size_t base = (size_t)(blockIdx.x * 256 + threadIdx.x) * 16;
#pragma unroll
    for (int j = 0; j < 4; ++j) {
        float4 f = *(const float4*)(s + base + j * 4);
        bf16x4 t;
        t[0] = (__bf16)f.x; t[1] = (__bf16)f.y; t[2] = (__bf16)f.z; t[3] = (__bf16)f.w;
        *(bf16x4*)(d + base + j * 4) = t;
    }
}

// ---------------------------------------------------------------------------
// LayerNorm -> bf16. One 256-thread block per token row
// ---------------------------------------------------------------------------
__global__ __launch_bounds__(256) void ln_kernel(
        const float* __restrict__ x, const float* __restrict__ gamma,
        const float* __restrict__ beta, __bf16* __restrict__ h) {
    int row = blockIdx.x;
    int tid = threadIdx.x;
    const float* xr = x + (size_t)row * EMB_;
    float4 v = *(const float4*)(xr + tid * 4);
    float s  = v.x + v.y + v.z + v.w;
    float ss = v.x * v.x + v.y * v.y + v.z * v.z + v.w * v.w;
    for (int off = 32; off; off >>= 1) {
        s  += __shfl_down(s, off, 64);
        ss += __shfl_down(ss, off, 64);
    }
    __shared__ float s1[4], s2[4];
    int wid = tid >> 6;
    if ((tid & 63) == 0) { s1[wid] = s; s2[wid] = ss; }
    __syncthreads();
    if (tid == 0) {
        float a = s1[0] + s1[1] + s1[2] + s1[3];
        float b = s2[0] + s2[1] + s2[2] + s2[3];
        float mu = a / EMB_;
        float var = b / EMB_ - mu * mu;
        s1[0] = mu;
        s2[0] = rsqrtf(var + 1e-5f);
    }
    __syncthreads();
    float mu = s1[0], rstd = s2[0];
    float4 g4 = *(const float4*)(gamma + tid * 4);
    float4 b4 = *(const float4*)(beta + tid * 4);
    bf16x4 o;
    o[0] = (__bf16)((v.x - mu) * rstd * g4.x + b4.x);
    o[1] = (__bf16)((v.y - mu) * rstd * g4.y + b4.y);
    o[2] = (__bf16)((v.z - mu) * rstd * g4.z + b4.z);
    o[3] = (__bf16)((v.w - mu) * rstd * g4.w + b4.w);
    *(bf16x4*)(h + (size_t)row * EMB_ + tid * 4) = o;
}

// ---------------------------------------------------------------------------
// GEMM staging: 128 rows x 64 cols bf16 tile, SWZ-swizzled 16B chunks.
// ---------------------------------------------------------------------------
__device__ __forceinline__ void stage_tile128(const __bf16* gbase, __bf16* lds,
                                              int wave, int lane) {
    int srow = lane >> 3;
    int gch0 = lane & 7;
#pragma unroll
    for (int s = 0; s < 4; ++s) {
        int seg = wave * 4 + s;
        int row = seg * 8 + srow;
        int g = gch0 ^ SWZ(row);
        __builtin_amdgcn_global_load_lds(
            (GV*)(gbase + (size_t)row * EMB_ + g * 8),
            (LV*)(lds + seg * 512 + lane * 8), 16, 0, 0);
    }
}

// ---------------------------------------------------------------------------
// Fused QKV projection GEMM: C = h @ Wqkv^T + bias, 128x128 tile, BK=64.
// Wqkv = [3072][1024] (Wq; Wk; Wv). Column block z = col>>10 selects output:
// z=0 -> Q (scaled by 0.125*log2e), z=1 -> K, z=2 -> V^T ([b][h][d][l]).
// ---------------------------------------------------------------------------
__global__ __launch_bounds__(256) void gemm_qkv_mfma(
        const __bf16* __restrict__ A, const __bf16* __restrict__ W,
        const float* __restrict__ bq, const float* __restrict__ bk,
        const float* __restrict__ bv,
        __bf16* __restrict__ Qo, __bf16* __restrict__ Ko,
        __bf16* __restrict__ Vto) {
    __shared__ __bf16 As[128 * 64];
    __shared__ __bf16 Bs[128 * 64];
    int tid = threadIdx.x, wave = tid >> 6, lane = tid & 63;
    int wm = wave >> 1, wn = wave & 1;
    int quad = lane >> 5, lq = lane & 31;
    int bm = blockIdx.y * 128, bn = blockIdx.x * 128;

    floatx16 acc[2][2];
#pragma unroll
    for (int i = 0; i < 2; ++i)
#pragma unroll
        for (int j = 0; j < 2; ++j)
#pragma unroll
            for (int r = 0; r < 16; ++r) acc[i][j][r] = 0.f;

    for (int k0 = 0; k0 < EMB_; k0 += 64) {
        __syncthreads();
        stage_tile128(A + (size_t)bm * EMB_ + k0, As, wave, lane);
        stage_tile128(W + (size_t)bn * EMB_ + k0, Bs, wave, lane);
        __syncthreads();
#pragma unroll
        for (int s = 0; s < 4; ++s) {
            int g = 2 * s + quad;
            int r0 = wm * 64 + lq, r1 = r0 + 32;
            int c0 = wn * 64 + lq, c1 = c0 + 32;
            bf16x8 a0 = *(const bf16x8*)&As[r0 * 64 + ((g ^ SWZ(r0)) * 8)];
            bf16x8 a1 = *(const bf16x8*)&As[r1 * 64 + ((g ^ SWZ(r1)) * 8)];
            bf16x8 b0 = *(const bf16x8*)&Bs[c0 * 64 + ((g ^ SWZ(c0)) * 8)];
            bf16x8 b1 = *(const bf16x8*)&Bs[c1 * 64 + ((g ^ SWZ(c1)) * 8)];
            acc[0][0] = MFMA32(a0, b0, acc[0][0]);
            acc[0][1] = MFMA32(a0, b1, acc[0][1]);
            acc[1][0] = MFMA32(a1, b0, acc[1][0]);
            acc[1][1] = MFMA32(a1, b1, acc[1][1]);
        }
    }

#pragma unroll
    for (int mb = 0; mb < 2; ++mb) {
#pragma unroll
        for (int nb = 0; nb < 2; ++nb) {
            int col = bn + wn * 64 + nb * 32 + lq;
            int z = col >> 10;
            int cc = col & 1023;
            float bv_ = (z == 0) ? bq[cc] : (z == 1) ? bk[cc] : bv[cc];
            if (z < 2) {
                __bf16* dst = (z == 0) ? Qo : Ko;
                float qs = (z == 0) ? 0.125f * LOG2E : 1.0f;
#pragma unroll
                for (int r = 0; r < 16; ++r) {
                    int row = bm + wm * 64 + mb * 32 + (r & 3) + 8 * (r >> 2) + 4 * quad;
                    dst[(size_t)row * EMB_ + cc] = (__bf16)((acc[mb][nb][r] + bv_) * qs);
                }
            } else {
                int hh = cc >> 6, d = cc & 63;
#pragma unroll
                for (int rb = 0; rb < 4; ++rb) {
                    int row = bm + wm * 64 + mb * 32 + 8 * rb + 4 * quad;
                    int b = row >> 11, l = row & (L_ - 1);
                    bf16x4 t;
#pragma unroll
                    for (int a = 0; a < 4; ++a) t[a] = (__bf16)(acc[mb][nb][4 * rb + a] + bv_);
                    *(bf16x4*)(Vto + ((size_t)(b * H_ + hh) * HD_ + d) * L_ + l) = t;
                }
            }
        }
    }
}

// ---------------------------------------------------------------------------
// Output projection GEMM: out = O @ Wo^T + bo + x (fp32 out). 64x128 tile.
// ---------------------------------------------------------------------------
template <int SEGS>
__device__ __forceinline__ void stage_tile(const __bf16* gbase, __bf16* lds,
                                           int wave, int lane) {
    int srow = lane >> 3;
    int gch0 = lane & 7;
#pragma unroll
    for (int s = 0; s < SEGS; ++s) {
        int seg = wave * SEGS + s;
        int row = seg * 8 + srow;
        int g = gch0 ^ SWZ(row);
        __builtin_amdgcn_global_load_lds(
            (GV*)(gbase + (size_t)row * EMB_ + g * 8),
            (LV*)(lds + seg * 512 + lane * 8), 16, 0, 0);
    }
}

__global__ __launch_bounds__(256) void gemm_out_mfma(
        const __bf16* __restrict__ A, const __bf16* __restrict__ W,
        const float* __restrict__ bias, const float* __restrict__ x,
        float* __restrict__ out) {
    __shared__ __bf16 As[64 * 64];
    __shared__ __bf16 Bs[128 * 64];
    int tid = threadIdx.x, wave = tid >> 6, lane = tid & 63;
    int quad = lane >> 5, lq = lane & 31;
    int bm = blockIdx.y * 64, bn = blockIdx.x * 128;

    floatx16 acc[2];
#pragma unroll
    for (int i = 0; i < 2; ++i)
#pragma unroll
        for (int r = 0; r < 16; ++r) acc[i][r] = 0.f;

    for (int k0 = 0; k0 < EMB_; k0 += 64) {
        __syncthreads();
        stage_tile<2>(A + (size_t)bm * EMB_ + k0, As, wave, lane);
        stage_tile<4>(W + (size_t)bn * EMB_ + k0, Bs, wave, lane);
        __syncthreads();
#pragma unroll
        for (int s = 0; s < 4; ++s) {
            int g = 2 * s + quad;
            int r0 = lq, r1 = lq + 32;
            int c = wave * 32 + lq;
            bf16x8 a0 = *(const bf16x8*)&As[r0 * 64 + ((g ^ SWZ(r0)) * 8)];
            bf16x8 a1 = *(const bf16x8*)&As[r1 * 64 + ((g ^ SWZ(r1)) * 8)];
            bf16x8 b  = *(const bf16x8*)&Bs[c * 64 + ((g ^ SWZ(c)) * 8)];
            acc[0] = MFMA32(a0, b, acc[0]);
            acc[1] = MFMA32(a1, b, acc[1]);
        }
    }

    int col = bn + wave * 32 + lq;
    float bv_ = bias[col];
#pragma unroll
    for (int mb = 0; mb < 2; ++mb) {
#pragma unroll
        for (int r = 0; r < 16; ++r) {
            size_t row = bm + mb * 32 + (r & 3) + 8 * (r >> 2) + 4 * quad;
            out[row * EMB_ + col] = acc[mb][r] + bv_ + x[row * EMB_ + col];
        }
    }
}

// ---------------------------------------------------------------------------
// LDS-staged, double-buffered MFMA flash attention — 32 queries per wave
// (halved register footprint vs the 64-q/wave version; no forced launch
// bound — letting the allocator pick, occupancy read from counters).
// Block = 256 thr (4 waves) covers 128 queries. Per 64-key tile: K and V^T
// staged via global_load_lds (coalesced, SWZ), fragments read b128.
// S^T = MFMA(K-frag, Q-frag): per-lane l; P fix-up via quad-half shuffle;
// O^T in C-layout [d][q] partials + combine kernel. blockIdx.x = bh.
// ---------------------------------------------------------------------------
__global__ __launch_bounds__(256) void attn_mfma(
        const __bf16* __restrict__ Q,   // [4096][1024], pre-scaled
        const __bf16* __restrict__ K,   // [4096][1024]
        const __bf16* __restrict__ Vt,  // [bh][64][2048]
        __bf16* __restrict__ Op,        // [KSPLIT][bh][64][2048]
        float* __restrict__ Lp) {       // [KSPLIT][bh][2048]
    __shared__ __bf16 Ks[2][64 * 64];
    __shared__ __bf16 Vs[2][64 * 64];

    int tid = threadIdx.x, wave = tid >> 6, lane = tid & 63;
    int quad = lane >> 5, lq = lane & 31;
    int bh = blockIdx.x;
    int ks = blockIdx.z;
    int b = bh >> 4, h = bh & 15;
    int q0 = blockIdx.y * 128 + wave * 32;
    const size_t tok0 = (size_t)b * L_;

    const __bf16* Kb = K + tok0 * EMB_ + h * HD_;
    const __bf16* Vb = Vt + (size_t)bh * HD_ * L_;

    // Q fragments: B-operand, 4 k-steps over d=64
    bf16x8 qf[4];
    {
        const __bf16* qp = Q + (tok0 + q0 + lq) * EMB_ + h * HD_ + quad * 8;
#pragma unroll
        for (int s = 0; s < 4; ++s) qf[s] = *(const bf16x8*)(qp + s * 16);
    }

    floatx16 oacc[2];   // [db]
#pragma unroll
    for (int j = 0; j < 2; ++j)
#pragma unroll
        for (int r = 0; r < 16; ++r) oacc[j][r] = 0.f;
    float lacc = 0.f;

    int srow = lane >> 3, gch0 = lane & 7;

    auto stage = [&](int buf, int kt) {
#pragma unroll
        for (int s = 0; s < 2; ++s) {
            int seg = wave * 2 + s;
            int row = seg * 8 + srow;
            int g = gch0 ^ SWZ(row);
            __builtin_amdgcn_global_load_lds(
                (GV*)(Kb + (size_t)(kt + row) * EMB_ + g * 8),
                (LV*)(&Ks[buf][seg * 512 + lane * 8]), 16, 0, 0);
            __builtin_amdgcn_global_load_lds(
                (GV*)(Vb + (size_t)row * L_ + kt + g * 8),
                (LV*)(&Vs[buf][seg * 512 + lane * 8]), 16, 0, 0);
        }
    };

    auto compute = [&](int buf) {
#pragma unroll
        for (int nb = 0; nb < 2; ++nb) {
            // K fragments (A-operand) for this 32-key block
            int krow = nb * 32 + lq;
            bf16x8 kf[4];
#pragma unroll
            for (int s = 0; s < 4; ++s)
                kf[s] = *(const bf16x8*)&Ks[buf][krow * 64 + (((2 * s + quad) ^ SWZ(krow)) * 8)];

            floatx16 sacc;
#pragma unroll
            for (int r = 0; r < 16; ++r) sacc[r] = 0.f;
#pragma unroll
            for (int s = 0; s < 4; ++s) sacc = MFMA32(kf[s], qf[s], sacc);

            int P[8];
            float lsum = 0.f;
#pragma unroll
            for (int t = 0; t < 8; ++t) {
                float pa = EXP2(sacc[2 * t]);
                float pb = EXP2(sacc[2 * t + 1]);
                lsum += pa + pb;
                P[t] = pkbf(pa, pb);
            }
            lacc += lsum;
            int X[8];
#pragma unroll
            for (int t = 0; t < 8; ++t) X[t] = __shfl_xor(P[t], 32, 64);
            union { int i[4]; bf16x8 v; } bf0, bf1;
            bf0.i[0] = quad ? X[2] : P[0];
            bf0.i[1] = quad ? X[3] : P[1];
            bf0.i[2] = quad ? P[2] : X[0];
            bf0.i[3] = quad ? P[3] : X[1];
            bf1.i[0] = quad ? X[6] : P[4];
            bf1.i[1] = quad ? X[7] : P[5];
            bf1.i[2] = quad ? P[6] : X[4];
            bf1.i[3] = quad ? P[7] : X[5];

            // V^T fragments for the two 16-key PV steps of this block
#pragma unroll
            for (int half = 0; half < 2; ++half) {
                int t = 2 * nb + half;
#pragma unroll
                for (int db = 0; db < 2; ++db) {
                    int drow = db * 32 + lq;
                    bf16x8 vf = *(const bf16x8*)&Vs[buf][drow * 64 + (((2 * t + quad) ^ SWZ(drow)) * 8)];
                    oacc[db] = MFMA32(vf, half ? bf1.v : bf0.v, oacc[db]);
                }
            }
        }
    };

    const int kt0 = ks * (L_ / KSPLIT);
    const int NT = (L_ / KSPLIT) / 64;   // 8 tiles of 64 keys

    stage(0, kt0);
    for (int t = 0; t < NT; ++t) {
        __syncthreads();                  // buf[t&1] staged (vmcnt drained)
        if (t + 1 < NT) stage((t + 1) & 1, kt0 + (t + 1) * 64);
        compute(t & 1);
    }

    // denominator: combine quad halves; lane<32 stores this wave's 32 queries
    {
        float l = lacc + __shfl_xor(lacc, 32, 64);
        if (lane < 32)
            Lp[((size_t)ks * 32 + bh) * L_ + q0 + lane] = l;
    }
    // store O^T partials in C-layout [d][q] (col q contiguous across lanes)
#pragma unroll
    for (int db = 0; db < 2; ++db)
#pragma unroll
        for (int r = 0; r < 16; ++r) {
            int dp = db * 32 + (r & 3) + 8 * (r >> 2) + 4 * quad;
            Op[((size_t)(ks * 32 + bh) * HD_ + dp) * L_ + q0 + lq] =
                (__bf16)oacc[db][r];
        }
}

// ---------------------------------------------------------------------------
// Combine split-K partials + transpose to token-major.
// ---------------------------------------------------------------------------
__global__ __launch_bounds__(256) void combine_kernel(
        const __bf16* __restrict__ Op, const float* __restrict__ Lp,
        __bf16* __restrict__ Ob) {
    __shared__ float lrl[64];
    __shared__ __bf16 T[64][72];   // [q][d]
    int t = threadIdx.x;
    int qt = blockIdx.x * 64;
    int bh = blockIdx.y;
    int b = bh >> 4, h = bh & 15;

    if (t < 64) {
        float l = 0.f;
#pragma unroll
        for (int ks = 0; ks < KSPLIT; ++ks)
            l += Lp[((size_t)ks * 32 + bh) * L_ + qt + t];
        lrl[t] = 1.0f / l;
    }
    __syncthreads();

#pragma unroll
    for (int cc = 0; cc < 2; ++cc) {
        int id = t + cc * 256;          // 0..511
        int d = id >> 3, q8 = (id & 7) * 8;
        float acc[8];
#pragma unroll
        for (int j = 0; j < 8; ++j) acc[j] = 0.f;
#pragma unroll
        for (int ks = 0; ks < KSPLIT; ++ks) {
            bf16x8 v = *(const bf16x8*)(Op + ((size_t)(ks * 32 + bh) * HD_ + d) * L_ + qt + q8);
#pragma unroll
            for (int j = 0; j < 8; ++j) acc[j] += (float)v[j];
        }
#pragma unroll
        for (int j = 0; j < 8; ++j)
            T[q8 + j][d] = (__bf16)(acc[j] * lrl[q8 + j]);
    }
    __syncthreads();

#pragma unroll
    for (int cc = 0; cc < 2; ++cc) {
        int id = t + cc * 256;
        int tl = id >> 3, dc = (id & 7) * 8;
        bf16x8 v = *(const bf16x8*)&T[tl][dc];
        *(bf16x8*)(Ob + ((size_t)b * L_ + qt + tl) * EMB_ + h * HD_ + dc) = v;
    }
}

// ---------------------------------------------------------------------------
extern "C" void kernel_launch(void* const* d_in, const int* in_sizes, int n_in,
                              void* d_out, int out_size, void* d_ws, size_t ws_size,
                              hipStream_t stream) {
    const float* x     = (const float*)d_in[0];
    const float* gamma = (const float*)d_in[1];
    const float* beta  = (const float*)d_in[2];
    const float* Wq    = (const float*)d_in[3];
    const float* bq    = (const float*)d_in[4];
    const float* Wk    = (const float*)d_in[5];
    const float* bk    = (const float*)d_in[6];
    const float* Wv    = (const float*)d_in[7];
    const float* bv    = (const float*)d_in[8];
    const float* Wo    = (const float*)d_in[9];
    const float* bo    = (const float*)d_in[10];
    float* out = (float*)d_out;

    const size_t SLAB = (size_t)M_ * EMB_;        // activation elements
    const size_t WSLAB = (size_t)EMB_ * EMB_;     // weight elements
    char* ws = (char*)d_ws;
    __bf16* hb    = (__bf16*)ws;                      ws += SLAB * 2;
    __bf16* Qb    = (__bf16*)ws;                      ws += SLAB * 2;
    __bf16* Kb    = (__bf16*)ws;                      ws += SLAB * 2;
    __bf16* Vtb   = (__bf16*)ws;                      ws += SLAB * 2;
    __bf16* Wqkvb = (__bf16*)ws;                      ws += 3 * WSLAB * 2;
    __bf16* Wob   = (__bf16*)ws;                      ws += WSLAB * 2;
    __bf16* Op    = (__bf16*)ws;                      ws += (size_t)KSPLIT * SLAB * 2;
    float*  Lp    = (float*)ws;                       ws += (size_t)KSPLIT * 32 * L_ * 4;
    __bf16* Ob    = hb;   // hb dead after gemm_qkv; reuse for attention output

    cvt_w_kernel<<<dim3(256, 4), 256, 0, stream>>>(
        Wq, Wk, Wv, Wo, Wqkvb, Wqkvb + WSLAB, Wqkvb + 2 * WSLAB, Wob);
    ln_kernel<<<M_, 256, 0, stream>>>(x, gamma, beta, hb);
    gemm_qkv_mfma<<<dim3(3 * EMB_ / 128, M_ / 128), 256, 0, stream>>>(
        hb, Wqkvb, bq, bk, bv, Qb, Kb, Vtb);
    attn_mfma<<<dim3(B_ * H_, L_ / 128, KSPLIT), 256, 0, stream>>>(Qb, Kb, Vtb, Op, Lp);
    combine_kernel<<<dim3(L_ / 64, B_ * H_), 256, 0, stream>>>(Op, Lp, Ob);
    gemm_out_mfma<<<dim3(EMB_ / 128, M_ / 64), 256, 0, stream>>>(Ob, Wob, bo, x, out);
}